// Round 2
// baseline (656.931 us; speedup 1.0000x reference)
//
#include <hip/hip_runtime.h>

#define IN_CH 128
#define NEG_SLOPE 0.2f

// ---------- 1) h = x @ W  (wave-per-row mat-vec) ----------
__global__ void proj_kernel(const float* __restrict__ x, const float* __restrict__ W,
                            float* __restrict__ h, int n) {
    int gtid   = blockIdx.x * blockDim.x + threadIdx.x;
    int wid    = gtid >> 6;
    int lane   = threadIdx.x & 63;
    int nwaves = (gridDim.x * blockDim.x) >> 6;

    // lane i holds W[2i], W[2i+1]
    float2 w2 = reinterpret_cast<const float2*>(W)[lane];

    for (int row = wid; row < n; row += nwaves) {
        float2 v = reinterpret_cast<const float2*>(x + (size_t)row * IN_CH)[lane];
        float s = v.x * w2.x + v.y * w2.y;
        // wave-64 butterfly reduce
        #pragma unroll
        for (int off = 32; off > 0; off >>= 1) s += __shfl_xor(s, off);
        if (lane == 0) h[row] = s;
    }
}

// ---------- 2) single pass over edges, no-max softmax via atomics ----------
__global__ void edge_kernel(const int* __restrict__ src_idx,
                            const int* __restrict__ dst_idx,
                            const float* __restrict__ h,
                            const float* __restrict__ att_src,
                            const float* __restrict__ att_dst,
                            float* __restrict__ nd, int E) {
    const float as = att_src[0];
    const float ad = att_dst[0];
    int i      = blockIdx.x * blockDim.x + threadIdx.x;
    int stride = gridDim.x * blockDim.x;
    for (; i < E; i += stride) {
        int s = src_idx[i];
        int d = dst_idx[i];
        float hs = h[s];
        float hd = h[d];
        float v  = fmaf(hs, as, hd * ad);
        float l  = v > 0.0f ? v : NEG_SLOPE * v;
        float e  = __expf(l);
        unsafeAtomicAdd(&nd[2 * d],     e * hs);  // numerator
        unsafeAtomicAdd(&nd[2 * d + 1], e);       // denominator
    }
}

// ---------- 3) fold in self-loop, divide, add bias ----------
__global__ void final_kernel(const float* __restrict__ h, const float* __restrict__ nd,
                             const float* __restrict__ att_src,
                             const float* __restrict__ att_dst,
                             const float* __restrict__ bias,
                             float* __restrict__ out, int n) {
    int i = blockIdx.x * blockDim.x + threadIdx.x;
    if (i >= n) return;
    float hv = h[i];
    float v  = hv * (att_src[0] + att_dst[0]);
    float l  = v > 0.0f ? v : NEG_SLOPE * v;
    float e  = __expf(l);
    float num = nd[2 * i]     + e * hv;
    float den = nd[2 * i + 1] + e + 1e-16f;
    out[i] = num / den + bias[0];
}

extern "C" void kernel_launch(void* const* d_in, const int* in_sizes, int n_in,
                              void* d_out, int out_size, void* d_ws, size_t ws_size,
                              hipStream_t stream) {
    const float* x       = (const float*)d_in[0];
    const int*   ei      = (const int*)d_in[1];   // int64 in reference -> int32 here
    const float* W       = (const float*)d_in[2];
    const float* att_src = (const float*)d_in[3];
    const float* att_dst = (const float*)d_in[4];
    const float* bias    = (const float*)d_in[5];
    float*       out     = (float*)d_out;

    const int n = out_size;           // 100000 nodes
    const int E = in_sizes[1] / 2;    // 6400000 edges

    // workspace layout: h [n floats] | nd [2n floats, {num,denom} interleaved]
    float* h  = (float*)d_ws;
    float* nd = (float*)((char*)d_ws + (((size_t)n * sizeof(float) + 255) & ~(size_t)255));

    hipMemsetAsync(nd, 0, (size_t)n * 2 * sizeof(float), stream);
    proj_kernel<<<2048, 256, 0, stream>>>(x, W, h, n);
    edge_kernel<<<2048, 256, 0, stream>>>(ei, ei + E, h, att_src, att_dst, nd, E);
    final_kernel<<<(n + 255) / 256, 256, 0, stream>>>(h, nd, att_src, att_dst, bias, out, n);
}

// Round 3
// 276.712 us; speedup vs baseline: 2.3741x; 2.3741x over previous
//
#include <hip/hip_runtime.h>

#define IN_CH 128
#define NEG_SLOPE 0.2f
#define BINSZ 8000          // nodes per bin; LDS = 2*8000*4 = 64000 B (< 64 KB static limit)
#define SCAN_THREADS 1024
#define MAX_BPB 40

// ---------- 1) h = x @ W  (wave-per-row mat-vec) ----------
__global__ void proj_kernel(const float* __restrict__ x, const float* __restrict__ W,
                            float* __restrict__ h, int n) {
    int gtid   = blockIdx.x * blockDim.x + threadIdx.x;
    int wid    = gtid >> 6;
    int lane   = threadIdx.x & 63;
    int nwaves = (gridDim.x * blockDim.x) >> 6;

    float2 w2 = reinterpret_cast<const float2*>(W)[lane];

    for (int row = wid; row < n; row += nwaves) {
        float2 v = reinterpret_cast<const float2*>(x + (size_t)row * IN_CH)[lane];
        float s = v.x * w2.x + v.y * w2.y;
        #pragma unroll
        for (int off = 32; off > 0; off >>= 1) s += __shfl_xor(s, off);
        if (lane == 0) h[row] = s;
    }
}

// ---------- 2a) binned scan: LDS-aggregate {num,den} per destination bin ----------
__global__ __launch_bounds__(SCAN_THREADS)
void scan_kernel(const int* __restrict__ src_idx, const int* __restrict__ dst_idx,
                 const float* __restrict__ h,
                 const float* __restrict__ att_src, const float* __restrict__ att_dst,
                 float* __restrict__ part, int E, int n, int BPB) {
    __shared__ float s_num[BINSZ];
    __shared__ float s_den[BINSZ];

    int bin   = blockIdx.x / BPB;
    int slice = blockIdx.x - bin * BPB;
    int base  = bin * BINSZ;
    int blen  = min(BINSZ, n - base);

    for (int k = threadIdx.x; k < BINSZ; k += SCAN_THREADS) { s_num[k] = 0.f; s_den[k] = 0.f; }
    __syncthreads();

    const float as = att_src[0];
    const float ad = att_dst[0];

    long long e0 = (long long)E * slice / BPB;
    long long e1 = (long long)E * (slice + 1) / BPB;
    for (long long i = e0 + threadIdx.x; i < e1; i += SCAN_THREADS) {
        int d = dst_idx[i];
        unsigned r = (unsigned)(d - base);
        if (r < (unsigned)blen) {
            int s = src_idx[i];
            float hs = h[s];
            float hd = h[d];
            float v  = fmaf(hs, as, hd * ad);
            float l  = v > 0.0f ? v : NEG_SLOPE * v;
            float e  = __expf(l);
            atomicAdd(&s_num[r], e * hs);   // ds_add_f32, fire-and-forget
            atomicAdd(&s_den[r], e);
        }
    }
    __syncthreads();

    float* outp = part + (size_t)blockIdx.x * (2 * BINSZ);
    for (int k = threadIdx.x; k < BINSZ; k += SCAN_THREADS) {
        outp[k]         = s_num[k];
        outp[BINSZ + k] = s_den[k];
    }
}

// ---------- 2b) reduce copies + self-loop + divide ----------
__global__ void reduce_final(const float* __restrict__ part, const float* __restrict__ h,
                             const float* __restrict__ att_src, const float* __restrict__ att_dst,
                             const float* __restrict__ bias, float* __restrict__ out,
                             int n, int BPB) {
    int i = blockIdx.x * blockDim.x + threadIdx.x;
    if (i >= n) return;
    int bin = i / BINSZ;
    int off = i - bin * BINSZ;
    float num = 0.f, den = 0.f;
    const float* p = part + (size_t)(bin * BPB) * (2 * BINSZ);
    for (int s = 0; s < BPB; ++s) {
        num += p[off];
        den += p[BINSZ + off];
        p += 2 * BINSZ;
    }
    float hv = h[i];
    float v  = hv * (att_src[0] + att_dst[0]);
    float l  = v > 0.0f ? v : NEG_SLOPE * v;
    float e  = __expf(l);
    out[i] = (num + e * hv) / (den + e + 1e-16f) + bias[0];
}

// ---------- fallback path (round-2 style global atomics) ----------
__global__ void edge_kernel(const int* __restrict__ src_idx, const int* __restrict__ dst_idx,
                            const float* __restrict__ h,
                            const float* __restrict__ att_src, const float* __restrict__ att_dst,
                            float* __restrict__ nd, int E) {
    const float as = att_src[0];
    const float ad = att_dst[0];
    int i      = blockIdx.x * blockDim.x + threadIdx.x;
    int stride = gridDim.x * blockDim.x;
    for (; i < E; i += stride) {
        int s = src_idx[i];
        int d = dst_idx[i];
        float hs = h[s];
        float hd = h[d];
        float v  = fmaf(hs, as, hd * ad);
        float l  = v > 0.0f ? v : NEG_SLOPE * v;
        float e  = __expf(l);
        unsafeAtomicAdd(&nd[2 * d],     e * hs);
        unsafeAtomicAdd(&nd[2 * d + 1], e);
    }
}

__global__ void final_kernel(const float* __restrict__ h, const float* __restrict__ nd,
                             const float* __restrict__ att_src, const float* __restrict__ att_dst,
                             const float* __restrict__ bias, float* __restrict__ out, int n) {
    int i = blockIdx.x * blockDim.x + threadIdx.x;
    if (i >= n) return;
    float hv = h[i];
    float v  = hv * (att_src[0] + att_dst[0]);
    float l  = v > 0.0f ? v : NEG_SLOPE * v;
    float e  = __expf(l);
    out[i] = (nd[2 * i] + e * hv) / (nd[2 * i + 1] + e + 1e-16f) + bias[0];
}

extern "C" void kernel_launch(void* const* d_in, const int* in_sizes, int n_in,
                              void* d_out, int out_size, void* d_ws, size_t ws_size,
                              hipStream_t stream) {
    const float* x       = (const float*)d_in[0];
    const int*   ei      = (const int*)d_in[1];   // int64 in reference -> int32 here
    const float* W       = (const float*)d_in[2];
    const float* att_src = (const float*)d_in[3];
    const float* att_dst = (const float*)d_in[4];
    const float* bias    = (const float*)d_in[5];
    float*       out     = (float*)d_out;

    const int n = out_size;           // 100000 nodes
    const int E = in_sizes[1] / 2;    // 6400000 edges

    const int nbins = (n + BINSZ - 1) / BINSZ;            // 13
    size_t hb  = (((size_t)n * sizeof(float)) + 255) & ~(size_t)255;
    size_t per = (size_t)2 * BINSZ * sizeof(float);       // 64 KB per block copy

    int BPB = 0;
    if (ws_size > hb) BPB = (int)((ws_size - hb) / ((size_t)nbins * per));
    if (BPB > MAX_BPB) BPB = MAX_BPB;

    float* h = (float*)d_ws;

    proj_kernel<<<2048, 256, 0, stream>>>(x, W, h, n);

    if (BPB >= 6) {
        // binned LDS path: no global atomics
        float* part = (float*)((char*)d_ws + hb);
        scan_kernel<<<nbins * BPB, SCAN_THREADS, 0, stream>>>(
            ei, ei + E, h, att_src, att_dst, part, E, n, BPB);
        reduce_final<<<(n + 255) / 256, 256, 0, stream>>>(
            part, h, att_src, att_dst, bias, out, n, BPB);
    } else {
        // fallback: global-atomic path
        float* nd = (float*)((char*)d_ws + hb);
        hipMemsetAsync(nd, 0, (size_t)n * 2 * sizeof(float), stream);
        edge_kernel<<<2048, 256, 0, stream>>>(ei, ei + E, h, att_src, att_dst, nd, E);
        final_kernel<<<(n + 255) / 256, 256, 0, stream>>>(h, nd, att_src, att_dst, bias, out, n);
    }
}

// Round 4
// 220.293 us; speedup vs baseline: 2.9821x; 1.2561x over previous
//
#include <hip/hip_runtime.h>

#define IN_CH 128
#define NEG_SLOPE 0.2f
#define BINSZ 8000          // nodes per bin; LDS = 2*8000*4 = 64000 B
#define NBINS 13
#define MAX_SG 40
#define MAX_BPB 40

// ---------- 1) h = x @ W  (wave-per-row mat-vec) ----------
__global__ void proj_kernel(const float* __restrict__ x, const float* __restrict__ W,
                            float* __restrict__ h, int n) {
    int gtid   = blockIdx.x * blockDim.x + threadIdx.x;
    int wid    = gtid >> 6;
    int lane   = threadIdx.x & 63;
    int nwaves = (gridDim.x * blockDim.x) >> 6;

    float2 w2 = reinterpret_cast<const float2*>(W)[lane];

    for (int row = wid; row < n; row += nwaves) {
        float2 v = reinterpret_cast<const float2*>(x + (size_t)row * IN_CH)[lane];
        float s = v.x * w2.x + v.y * w2.y;
        #pragma unroll
        for (int off = 32; off > 0; off >>= 1) s += __shfl_xor(s, off);
        if (lane == 0) h[row] = s;
    }
}

// ---------- 2a) histogram of destination bins ----------
__global__ __launch_bounds__(1024)
void hist_kernel(const int* __restrict__ dst_idx, int* __restrict__ hist, int E) {
    __shared__ int lh[NBINS];
    if (threadIdx.x < NBINS) lh[threadIdx.x] = 0;
    __syncthreads();
    int i = blockIdx.x * blockDim.x + threadIdx.x;
    int stride = gridDim.x * blockDim.x;
    for (; i < E; i += stride) {
        int b = dst_idx[i] / BINSZ;
        atomicAdd(&lh[b], 1);
    }
    __syncthreads();
    if (threadIdx.x < NBINS) atomicAdd(&hist[threadIdx.x], lh[threadIdx.x]);
}

// ---------- 2b) 13-element exclusive scan + cursor init ----------
__global__ void scan13_kernel(const int* __restrict__ hist, int* __restrict__ rbase,
                              int* __restrict__ cursor) {
    if (threadIdx.x == 0 && blockIdx.x == 0) {
        int acc = 0;
        for (int b = 0; b < NBINS; ++b) {
            rbase[b] = acc; cursor[b] = acc; acc += hist[b];
        }
    }
}

// ---------- 2c) scatter: compute {e, e*hs} once, bin-append records ----------
__global__ __launch_bounds__(1024)
void scatter_kernel(const int* __restrict__ src_idx, const int* __restrict__ dst_idx,
                    const float* __restrict__ h,
                    const float* __restrict__ att_src, const float* __restrict__ att_dst,
                    int* __restrict__ cursor,
                    unsigned short* __restrict__ rr, float2* __restrict__ vv, int E) {
    __shared__ int lcnt[NBINS];
    __shared__ int lbase[NBINS];
    const float as = att_src[0];
    const float ad = att_dst[0];

    long long c0 = (long long)E * blockIdx.x / gridDim.x;
    long long c1 = (long long)E * (blockIdx.x + 1) / gridDim.x;

    for (long long base = c0; base < c1; base += blockDim.x) {
        long long i = base + threadIdx.x;
        bool valid = (i < c1);
        int b = 0, r = 0, rank = 0;
        float e = 0.f, ehs = 0.f;

        if (threadIdx.x < NBINS) lcnt[threadIdx.x] = 0;
        __syncthreads();

        if (valid) {
            int d = dst_idx[i];
            int s = src_idx[i];
            float hs = h[s];
            float hd = h[d];
            float v  = fmaf(hs, as, hd * ad);
            float l  = v > 0.0f ? v : NEG_SLOPE * v;
            e   = __expf(l);
            ehs = e * hs;
            b = d / BINSZ;
            r = d - b * BINSZ;
            rank = atomicAdd(&lcnt[b], 1);
        }
        __syncthreads();
        if (threadIdx.x < NBINS)
            lbase[threadIdx.x] = atomicAdd(&cursor[threadIdx.x], lcnt[threadIdx.x]);
        __syncthreads();
        if (valid) {
            int pos = lbase[b] + rank;
            rr[pos] = (unsigned short)r;
            vv[pos] = make_float2(e, ehs);
        }
    }
}

// ---------- 2d) gather: dense per-bin aggregation ----------
__global__ __launch_bounds__(1024)
void gather_kernel(const unsigned short* __restrict__ rr, const float2* __restrict__ vv,
                   const int* __restrict__ rbase, const int* __restrict__ hist,
                   float* __restrict__ part, int SG) {
    __shared__ float s_num[BINSZ];
    __shared__ float s_den[BINSZ];

    int bin   = blockIdx.x / SG;
    int slice = blockIdx.x - bin * SG;
    int r0    = rbase[bin];
    int cnt   = hist[bin];
    long long g0 = r0 + (long long)cnt * slice / SG;
    long long g1 = r0 + (long long)cnt * (slice + 1) / SG;

    for (int k = threadIdx.x; k < BINSZ; k += 1024) { s_num[k] = 0.f; s_den[k] = 0.f; }
    __syncthreads();

    for (long long i = g0 + threadIdx.x; i < g1; i += 1024) {
        int r = rr[i];
        float2 v = vv[i];           // {e, e*hs}
        atomicAdd(&s_num[r], v.y);
        atomicAdd(&s_den[r], v.x);
    }
    __syncthreads();

    float* outp = part + (size_t)blockIdx.x * (2 * BINSZ);
    for (int k = threadIdx.x; k < BINSZ; k += 1024) {
        outp[k]         = s_num[k];
        outp[BINSZ + k] = s_den[k];
    }
}

// ---------- 3) reduce copies + self-loop + divide ----------
__global__ void reduce_final(const float* __restrict__ part, const float* __restrict__ h,
                             const float* __restrict__ att_src, const float* __restrict__ att_dst,
                             const float* __restrict__ bias, float* __restrict__ out,
                             int n, int SG) {
    int i = blockIdx.x * blockDim.x + threadIdx.x;
    if (i >= n) return;
    int bin = i / BINSZ;
    int off = i - bin * BINSZ;
    float num = 0.f, den = 0.f;
    const float* p = part + (size_t)(bin * SG) * (2 * BINSZ);
    for (int s = 0; s < SG; ++s) {
        num += p[off];
        den += p[BINSZ + off];
        p += 2 * BINSZ;
    }
    float hv = h[i];
    float v  = hv * (att_src[0] + att_dst[0]);
    float l  = v > 0.0f ? v : NEG_SLOPE * v;
    float e  = __expf(l);
    out[i] = (num + e * hv) / (den + e + 1e-16f) + bias[0];
}

// ---------- fallback: round-3 binned multipass ----------
__global__ __launch_bounds__(1024)
void binpass_kernel(const int* __restrict__ src_idx, const int* __restrict__ dst_idx,
                    const float* __restrict__ h,
                    const float* __restrict__ att_src, const float* __restrict__ att_dst,
                    float* __restrict__ part, int E, int n, int BPB) {
    __shared__ float s_num[BINSZ];
    __shared__ float s_den[BINSZ];

    int bin   = blockIdx.x / BPB;
    int slice = blockIdx.x - bin * BPB;
    int base  = bin * BINSZ;
    int blen  = min(BINSZ, n - base);

    for (int k = threadIdx.x; k < BINSZ; k += 1024) { s_num[k] = 0.f; s_den[k] = 0.f; }
    __syncthreads();

    const float as = att_src[0];
    const float ad = att_dst[0];

    long long e0 = (long long)E * slice / BPB;
    long long e1 = (long long)E * (slice + 1) / BPB;
    for (long long i = e0 + threadIdx.x; i < e1; i += 1024) {
        int d = dst_idx[i];
        unsigned r = (unsigned)(d - base);
        if (r < (unsigned)blen) {
            int s = src_idx[i];
            float hs = h[s];
            float hd = h[d];
            float v  = fmaf(hs, as, hd * ad);
            float l  = v > 0.0f ? v : NEG_SLOPE * v;
            float e  = __expf(l);
            atomicAdd(&s_num[r], e * hs);
            atomicAdd(&s_den[r], e);
        }
    }
    __syncthreads();

    float* outp = part + (size_t)blockIdx.x * (2 * BINSZ);
    for (int k = threadIdx.x; k < BINSZ; k += 1024) {
        outp[k]         = s_num[k];
        outp[BINSZ + k] = s_den[k];
    }
}

__global__ void edge_kernel(const int* __restrict__ src_idx, const int* __restrict__ dst_idx,
                            const float* __restrict__ h,
                            const float* __restrict__ att_src, const float* __restrict__ att_dst,
                            float* __restrict__ nd, int E) {
    const float as = att_src[0];
    const float ad = att_dst[0];
    int i      = blockIdx.x * blockDim.x + threadIdx.x;
    int stride = gridDim.x * blockDim.x;
    for (; i < E; i += stride) {
        int s = src_idx[i];
        int d = dst_idx[i];
        float hs = h[s];
        float hd = h[d];
        float v  = fmaf(hs, as, hd * ad);
        float l  = v > 0.0f ? v : NEG_SLOPE * v;
        float e  = __expf(l);
        unsafeAtomicAdd(&nd[2 * d],     e * hs);
        unsafeAtomicAdd(&nd[2 * d + 1], e);
    }
}

__global__ void final_kernel(const float* __restrict__ h, const float* __restrict__ nd,
                             const float* __restrict__ att_src, const float* __restrict__ att_dst,
                             const float* __restrict__ bias, float* __restrict__ out, int n) {
    int i = blockIdx.x * blockDim.x + threadIdx.x;
    if (i >= n) return;
    float hv = h[i];
    float v  = hv * (att_src[0] + att_dst[0]);
    float l  = v > 0.0f ? v : NEG_SLOPE * v;
    float e  = __expf(l);
    out[i] = (nd[2 * i] + e * hv) / (nd[2 * i + 1] + e + 1e-16f) + bias[0];
}

extern "C" void kernel_launch(void* const* d_in, const int* in_sizes, int n_in,
                              void* d_out, int out_size, void* d_ws, size_t ws_size,
                              hipStream_t stream) {
    const float* x       = (const float*)d_in[0];
    const int*   ei      = (const int*)d_in[1];   // int64 in reference -> int32 here
    const float* W       = (const float*)d_in[2];
    const float* att_src = (const float*)d_in[3];
    const float* att_dst = (const float*)d_in[4];
    const float* bias    = (const float*)d_in[5];
    float*       out     = (float*)d_out;

    const int n = out_size;           // 100000
    const int E = in_sizes[1] / 2;    // 6400000

    // ---- workspace layout ----
    size_t off = 0;
    auto alloc = [&](size_t bytes) { size_t p = off; off = (off + bytes + 255) & ~(size_t)255; return p; };
    size_t o_h    = alloc((size_t)n * sizeof(float));
    size_t o_meta = alloc(64 * sizeof(int));            // hist[13] | rbase[13] | cursor[13]
    size_t o_rr   = alloc((size_t)E * sizeof(unsigned short));
    size_t o_vv   = alloc((size_t)E * sizeof(float2));
    size_t fixed  = off;

    float* h = (float*)((char*)d_ws + o_h);
    const size_t per = (size_t)2 * BINSZ * sizeof(float);   // 64000 B per partial copy

    proj_kernel<<<2048, 256, 0, stream>>>(x, W, h, n);

    int SG = 0;
    if (ws_size > fixed) SG = (int)((ws_size - fixed) / ((size_t)NBINS * per));
    if (SG > MAX_SG) SG = MAX_SG;

    if (SG >= 8) {
        // ---- primary: counting-sort by destination bin, then dense aggregate ----
        int*   hist   = (int*)((char*)d_ws + o_meta);
        int*   rbase  = hist + NBINS;
        int*   cursor = hist + 2 * NBINS;
        unsigned short* rr = (unsigned short*)((char*)d_ws + o_rr);
        float2*         vv = (float2*)((char*)d_ws + o_vv);
        float*          part = (float*)((char*)d_ws + fixed);

        hipMemsetAsync(hist, 0, 64 * sizeof(int), stream);
        hist_kernel<<<512, 1024, 0, stream>>>(ei + E, hist, E);
        scan13_kernel<<<1, 64, 0, stream>>>(hist, rbase, cursor);
        scatter_kernel<<<512, 1024, 0, stream>>>(ei, ei + E, h, att_src, att_dst,
                                                 cursor, rr, vv, E);
        gather_kernel<<<NBINS * SG, 1024, 0, stream>>>(rr, vv, rbase, hist, part, SG);
        reduce_final<<<(n + 255) / 256, 256, 0, stream>>>(part, h, att_src, att_dst,
                                                          bias, out, n, SG);
    } else {
        // ---- fallback: round-3 multipass ----
        size_t hb = (((size_t)n * sizeof(float)) + 255) & ~(size_t)255;
        int BPB = 0;
        if (ws_size > hb) BPB = (int)((ws_size - hb) / ((size_t)NBINS * per));
        if (BPB > MAX_BPB) BPB = MAX_BPB;

        if (BPB >= 6) {
            float* part = (float*)((char*)d_ws + hb);
            binpass_kernel<<<NBINS * BPB, 1024, 0, stream>>>(
                ei, ei + E, h, att_src, att_dst, part, E, n, BPB);
            reduce_final<<<(n + 255) / 256, 256, 0, stream>>>(
                part, h, att_src, att_dst, bias, out, n, BPB);
        } else {
            float* nd = (float*)((char*)d_ws + hb);
            hipMemsetAsync(nd, 0, (size_t)n * 2 * sizeof(float), stream);
            edge_kernel<<<2048, 256, 0, stream>>>(ei, ei + E, h, att_src, att_dst, nd, E);
            final_kernel<<<(n + 255) / 256, 256, 0, stream>>>(h, nd, att_src, att_dst,
                                                              bias, out, n);
        }
    }
}

// Round 5
// 199.442 us; speedup vs baseline: 3.2938x; 1.1045x over previous
//
#include <hip/hip_runtime.h>

#define IN_CH 128
#define NEG_SLOPE 0.2f
#define BINSZ 8000          // nodes per bin; LDS = 2*8000*4 = 64000 B
#define NBINS 13
#define NW 8192             // global wave count for count/place (must match grids)
#define MAX_SG 32
#define MAX_BPB 40

// ---------- 1) h = x @ W  (wave-per-row mat-vec); also ad_h = h*att_dst ----------
__global__ void proj_kernel(const float* __restrict__ x, const float* __restrict__ W,
                            const float* __restrict__ att_dst,
                            float* __restrict__ h, float* __restrict__ ad_h, int n) {
    int gtid   = blockIdx.x * blockDim.x + threadIdx.x;
    int wid    = gtid >> 6;
    int lane   = threadIdx.x & 63;
    int nwaves = (gridDim.x * blockDim.x) >> 6;

    float2 w2 = reinterpret_cast<const float2*>(W)[lane];
    const float ad = att_dst[0];

    for (int row = wid; row < n; row += nwaves) {
        float2 v = reinterpret_cast<const float2*>(x + (size_t)row * IN_CH)[lane];
        float s = v.x * w2.x + v.y * w2.y;
        #pragma unroll
        for (int off = 32; off > 0; off >>= 1) s += __shfl_xor(s, off);
        if (lane == 0) { h[row] = s; ad_h[row] = s * ad; }
    }
}

// ---------- 2a) per-wave bin counts (no atomics) ----------
__global__ __launch_bounds__(256)
void count_kernel(const int* __restrict__ dst_idx, int* __restrict__ wc, int E) {
    int lane = threadIdx.x & 63;
    int g    = blockIdx.x * (blockDim.x >> 6) + (threadIdx.x >> 6);  // global wave id
    long long e0 = (long long)E * g / NW;
    long long e1 = (long long)E * (g + 1) / NW;

    int cnt = 0;  // lane b (b<13) accumulates count of bin b
    for (long long i0 = e0; i0 < e1; i0 += 64) {
        long long i = i0 + lane;
        bool valid = (i < e1);
        int b = valid ? dst_idx[i] / BINSZ : NBINS;
        #pragma unroll
        for (int b2 = 0; b2 < NBINS; ++b2) {
            unsigned long long m = __ballot(b == b2);
            if (lane == b2) cnt += __popcll(m);
        }
    }
    if (lane < NBINS) wc[lane * NW + g] = cnt;
}

// ---------- 2b) exclusive scan of wc[13*NW] -> wbase; emit rbase/hist ----------
__global__ __launch_bounds__(1024)
void scan_kernel(const int* __restrict__ wc, int* __restrict__ wbase,
                 int* __restrict__ rbase, int* __restrict__ hist) {
    const int NELEM = NBINS * NW;              // 106496
    const int CHUNK = NELEM / 1024;            // 104
    __shared__ int wtot[16];

    int t    = threadIdx.x;
    int lane = t & 63;
    int wv   = t >> 6;
    int base = t * CHUNK;

    int sum = 0;
    for (int j = 0; j < CHUNK; ++j) sum += wc[base + j];

    // inclusive scan within wave
    int v = sum;
    #pragma unroll
    for (int d = 1; d < 64; d <<= 1) {
        int u = __shfl_up(v, d);
        if (lane >= d) v += u;
    }
    if (lane == 63) wtot[wv] = v;
    __syncthreads();
    if (wv == 0) {
        int w = (lane < 16) ? wtot[lane] : 0;
        #pragma unroll
        for (int d = 1; d < 16; d <<= 1) {
            int u = __shfl_up(w, d);
            if (lane >= d) w += u;
        }
        if (lane < 16) wtot[lane] = w;   // inclusive wave totals
    }
    __syncthreads();
    int wb   = (wv == 0) ? 0 : wtot[wv - 1];
    int excl = wb + v - sum;

    int run = excl;
    for (int j = 0; j < CHUNK; ++j) { wbase[base + j] = run; run += wc[base + j]; }
    __syncthreads();

    if (t < NBINS) {
        int total = wtot[15];
        int rb = wbase[t * NW];
        rbase[t] = rb;
        int nb = (t < NBINS - 1) ? wbase[(t + 1) * NW] : total;
        hist[t] = nb - rb;
    }
}

// ---------- 2c) place: deterministic scatter of packed (r|s) records ----------
__global__ __launch_bounds__(256)
void place_kernel(const int* __restrict__ src_idx, const int* __restrict__ dst_idx,
                  const int* __restrict__ wbase, unsigned int* __restrict__ rec, int E) {
    int lane = threadIdx.x & 63;
    int g    = blockIdx.x * (blockDim.x >> 6) + (threadIdx.x >> 6);
    long long e0 = (long long)E * g / NW;
    long long e1 = (long long)E * (g + 1) / NW;

    int cur = (lane < NBINS) ? wbase[lane * NW + g] : 0;  // lane b: cursor for bin b
    unsigned long long ltmask = (1ULL << lane) - 1;

    for (long long i0 = e0; i0 < e1; i0 += 64) {
        long long i = i0 + lane;
        bool valid = (i < e1);
        int d = valid ? dst_idx[i] : 0;
        int s = valid ? src_idx[i] : 0;
        int b = valid ? d / BINSZ : NBINS;
        int r = d - (d / BINSZ) * BINSZ;
        int pos = 0;
        #pragma unroll
        for (int b2 = 0; b2 < NBINS; ++b2) {
            unsigned long long m = __ballot(b == b2);
            int base_b = __shfl(cur, b2);
            if (b == b2) pos = base_b + __popcll(m & ltmask);
            if (lane == b2) cur += __popcll(m);
        }
        if (valid) rec[pos] = ((unsigned int)r << 17) | (unsigned int)s;
    }
}

// ---------- 2d) gather: dense per-bin aggregation from packed records ----------
__global__ __launch_bounds__(1024)
void gather_kernel(const unsigned int* __restrict__ rec,
                   const float* __restrict__ h, const float* __restrict__ ad_h,
                   const float* __restrict__ att_src,
                   const int* __restrict__ rbase, const int* __restrict__ hist,
                   float* __restrict__ part, int SG) {
    __shared__ float s_num[BINSZ];
    __shared__ float s_den[BINSZ];

    int bin   = blockIdx.x / SG;
    int slice = blockIdx.x - bin * SG;
    int r0    = rbase[bin];
    int cnt   = hist[bin];
    long long g0 = r0 + (long long)cnt * slice / SG;
    long long g1 = r0 + (long long)cnt * (slice + 1) / SG;

    for (int k = threadIdx.x; k < BINSZ; k += 1024) { s_num[k] = 0.f; s_den[k] = 0.f; }
    __syncthreads();

    const float as = att_src[0];
    const float* adw = ad_h + bin * BINSZ;    // 32 KB window, L1-resident

    for (long long i = g0 + threadIdx.x; i < g1; i += 1024) {
        unsigned int p = rec[i];
        int s = p & 0x1FFFFu;
        int r = p >> 17;
        float hs = h[s];
        float v  = fmaf(hs, as, adw[r]);
        float l  = v > 0.0f ? v : NEG_SLOPE * v;
        float e  = __expf(l);
        atomicAdd(&s_num[r], e * hs);
        atomicAdd(&s_den[r], e);
    }
    __syncthreads();

    float* outp = part + (size_t)blockIdx.x * (2 * BINSZ);
    for (int k = threadIdx.x; k < BINSZ; k += 1024) {
        outp[k]         = s_num[k];
        outp[BINSZ + k] = s_den[k];
    }
}

// ---------- 3) reduce copies + self-loop + divide ----------
__global__ void reduce_final(const float* __restrict__ part, const float* __restrict__ h,
                             const float* __restrict__ att_src, const float* __restrict__ att_dst,
                             const float* __restrict__ bias, float* __restrict__ out,
                             int n, int SG) {
    int i = blockIdx.x * blockDim.x + threadIdx.x;
    if (i >= n) return;
    int bin = i / BINSZ;
    int off = i - bin * BINSZ;
    float num = 0.f, den = 0.f;
    const float* p = part + (size_t)(bin * SG) * (2 * BINSZ);
    for (int s = 0; s < SG; ++s) {
        num += p[off];
        den += p[BINSZ + off];
        p += 2 * BINSZ;
    }
    float hv = h[i];
    float v  = hv * (att_src[0] + att_dst[0]);
    float l  = v > 0.0f ? v : NEG_SLOPE * v;
    float e  = __expf(l);
    out[i] = (num + e * hv) / (den + e + 1e-16f) + bias[0];
}

// ---------- fallback: round-3 binned multipass ----------
__global__ __launch_bounds__(1024)
void binpass_kernel(const int* __restrict__ src_idx, const int* __restrict__ dst_idx,
                    const float* __restrict__ h,
                    const float* __restrict__ att_src, const float* __restrict__ att_dst,
                    float* __restrict__ part, int E, int n, int BPB) {
    __shared__ float s_num[BINSZ];
    __shared__ float s_den[BINSZ];

    int bin   = blockIdx.x / BPB;
    int slice = blockIdx.x - bin * BPB;
    int base  = bin * BINSZ;
    int blen  = min(BINSZ, n - base);

    for (int k = threadIdx.x; k < BINSZ; k += 1024) { s_num[k] = 0.f; s_den[k] = 0.f; }
    __syncthreads();

    const float as = att_src[0];
    const float ad = att_dst[0];

    long long e0 = (long long)E * slice / BPB;
    long long e1 = (long long)E * (slice + 1) / BPB;
    for (long long i = e0 + threadIdx.x; i < e1; i += 1024) {
        int d = dst_idx[i];
        unsigned r = (unsigned)(d - base);
        if (r < (unsigned)blen) {
            int s = src_idx[i];
            float hs = h[s];
            float hd = h[d];
            float v  = fmaf(hs, as, hd * ad);
            float l  = v > 0.0f ? v : NEG_SLOPE * v;
            float e  = __expf(l);
            atomicAdd(&s_num[r], e * hs);
            atomicAdd(&s_den[r], e);
        }
    }
    __syncthreads();

    float* outp = part + (size_t)blockIdx.x * (2 * BINSZ);
    for (int k = threadIdx.x; k < BINSZ; k += 1024) {
        outp[k]         = s_num[k];
        outp[BINSZ + k] = s_den[k];
    }
}

__global__ void edge_kernel(const int* __restrict__ src_idx, const int* __restrict__ dst_idx,
                            const float* __restrict__ h,
                            const float* __restrict__ att_src, const float* __restrict__ att_dst,
                            float* __restrict__ nd, int E) {
    const float as = att_src[0];
    const float ad = att_dst[0];
    int i      = blockIdx.x * blockDim.x + threadIdx.x;
    int stride = gridDim.x * blockDim.x;
    for (; i < E; i += stride) {
        int s = src_idx[i];
        int d = dst_idx[i];
        float hs = h[s];
        float hd = h[d];
        float v  = fmaf(hs, as, hd * ad);
        float l  = v > 0.0f ? v : NEG_SLOPE * v;
        float e  = __expf(l);
        unsafeAtomicAdd(&nd[2 * d],     e * hs);
        unsafeAtomicAdd(&nd[2 * d + 1], e);
    }
}

__global__ void final_kernel(const float* __restrict__ h, const float* __restrict__ nd,
                             const float* __restrict__ att_src, const float* __restrict__ att_dst,
                             const float* __restrict__ bias, float* __restrict__ out, int n) {
    int i = blockIdx.x * blockDim.x + threadIdx.x;
    if (i >= n) return;
    float hv = h[i];
    float v  = hv * (att_src[0] + att_dst[0]);
    float l  = v > 0.0f ? v : NEG_SLOPE * v;
    float e  = __expf(l);
    out[i] = (nd[2 * i] + e * hv) / (nd[2 * i + 1] + e + 1e-16f) + bias[0];
}

extern "C" void kernel_launch(void* const* d_in, const int* in_sizes, int n_in,
                              void* d_out, int out_size, void* d_ws, size_t ws_size,
                              hipStream_t stream) {
    const float* x       = (const float*)d_in[0];
    const int*   ei      = (const int*)d_in[1];   // int64 in reference -> int32 here
    const float* W       = (const float*)d_in[2];
    const float* att_src = (const float*)d_in[3];
    const float* att_dst = (const float*)d_in[4];
    const float* bias    = (const float*)d_in[5];
    float*       out     = (float*)d_out;

    const int n = out_size;           // 100000
    const int E = in_sizes[1] / 2;    // 6400000

    // ---- workspace layout ----
    size_t off = 0;
    auto alloc = [&](size_t bytes) { size_t p = off; off = (off + bytes + 255) & ~(size_t)255; return p; };
    size_t o_h    = alloc((size_t)n * sizeof(float));
    size_t o_adh  = alloc((size_t)n * sizeof(float));
    size_t o_wc   = alloc((size_t)NBINS * NW * sizeof(int));
    size_t o_wb   = alloc((size_t)NBINS * NW * sizeof(int));
    size_t o_meta = alloc(64 * sizeof(int));            // rbase[13] | hist[13]
    size_t o_rec  = alloc((size_t)E * sizeof(unsigned int));
    size_t fixed  = off;

    float* h    = (float*)((char*)d_ws + o_h);
    float* ad_h = (float*)((char*)d_ws + o_adh);
    const size_t per = (size_t)2 * BINSZ * sizeof(float);   // 64000 B per partial copy

    proj_kernel<<<2048, 256, 0, stream>>>(x, W, att_dst, h, ad_h, n);

    int SG = 0;
    if (ws_size > fixed) SG = (int)((ws_size - fixed) / ((size_t)NBINS * per));
    if (SG > MAX_SG) SG = MAX_SG;

    if (SG >= 8) {
        // ---- primary: deterministic counting sort + dense gather ----
        int*          wc    = (int*)((char*)d_ws + o_wc);
        int*          wb    = (int*)((char*)d_ws + o_wb);
        int*          rbase = (int*)((char*)d_ws + o_meta);
        int*          hist  = rbase + NBINS;
        unsigned int* rec   = (unsigned int*)((char*)d_ws + o_rec);
        float*        part  = (float*)((char*)d_ws + fixed);

        count_kernel<<<NW / 4, 256, 0, stream>>>(ei + E, wc, E);
        scan_kernel<<<1, 1024, 0, stream>>>(wc, wb, rbase, hist);
        place_kernel<<<NW / 4, 256, 0, stream>>>(ei, ei + E, wb, rec, E);
        gather_kernel<<<NBINS * SG, 1024, 0, stream>>>(rec, h, ad_h, att_src,
                                                       rbase, hist, part, SG);
        reduce_final<<<(n + 255) / 256, 256, 0, stream>>>(part, h, att_src, att_dst,
                                                          bias, out, n, SG);
    } else {
        // ---- fallback: round-3 multipass ----
        size_t hb = (((size_t)n * 2 * sizeof(float)) + 255) & ~(size_t)255;
        int BPB = 0;
        if (ws_size > hb) BPB = (int)((ws_size - hb) / ((size_t)NBINS * per));
        if (BPB > MAX_BPB) BPB = MAX_BPB;

        if (BPB >= 6) {
            float* part = (float*)((char*)d_ws + hb);
            binpass_kernel<<<NBINS * BPB, 1024, 0, stream>>>(
                ei, ei + E, h, att_src, att_dst, part, E, n, BPB);
            reduce_final<<<(n + 255) / 256, 256, 0, stream>>>(
                part, h, att_src, att_dst, bias, out, n, BPB);
        } else {
            float* nd = (float*)((char*)d_ws + hb);
            hipMemsetAsync(nd, 0, (size_t)n * 2 * sizeof(float), stream);
            edge_kernel<<<2048, 256, 0, stream>>>(ei, ei + E, h, att_src, att_dst, nd, E);
            final_kernel<<<(n + 255) / 256, 256, 0, stream>>>(h, nd, att_src, att_dst,
                                                              bias, out, n);
        }
    }
}

// Round 6
// 156.415 us; speedup vs baseline: 4.1999x; 1.2751x over previous
//
#include <hip/hip_runtime.h>

#define IN_CH 128
#define NEG_SLOPE 0.2f
#define BINSZ 8000          // nodes per bin; LDS = 2*8000*4 = 64000 B
#define NBINS 13
#define NW 8192             // global wave count for count/place (must match grids)
#define MAX_SG 39           // 13*39 = 507 blocks ~= 2 per CU
#define MAX_BPB 40

// ---------- 1) h = x @ W  (half-wave-per-row, float4); also ad_h = h*att_dst ----------
__global__ void proj_kernel(const float* __restrict__ x, const float* __restrict__ W,
                            const float* __restrict__ att_dst,
                            float* __restrict__ h, float* __restrict__ ad_h, int n) {
    int gtid   = blockIdx.x * blockDim.x + threadIdx.x;
    int wid    = gtid >> 6;
    int lane   = threadIdx.x & 63;
    int nwaves = (gridDim.x * blockDim.x) >> 6;
    int half   = lane >> 5;           // 0: even row, 1: odd row
    int hl     = lane & 31;

    float4 w4 = reinterpret_cast<const float4*>(W)[hl];
    const float ad = att_dst[0];

    int npair = n >> 1;
    for (int p = wid; p < npair; p += nwaves) {
        int row = 2 * p + half;
        float4 v = reinterpret_cast<const float4*>(x + (size_t)row * IN_CH)[hl];
        float s = v.x * w4.x + v.y * w4.y + v.z * w4.z + v.w * w4.w;
        #pragma unroll
        for (int off = 16; off > 0; off >>= 1) s += __shfl_xor(s, off);
        if (hl == 0) { h[row] = s; ad_h[row] = s * ad; }
    }
    // odd n tail (not hit for n=100000)
    if ((n & 1) && wid == 0) {
        int row = n - 1;
        float4 v = reinterpret_cast<const float4*>(x + (size_t)row * IN_CH)[hl];
        float s = v.x * w4.x + v.y * w4.y + v.z * w4.z + v.w * w4.w;
        #pragma unroll
        for (int off = 16; off > 0; off >>= 1) s += __shfl_xor(s, off);
        if (lane == 0) { h[row] = s; ad_h[row] = s * ad; }
    }
}

// ---------- 2a) per-wave bin counts via LDS counters ----------
__global__ __launch_bounds__(256)
void count_kernel(const int* __restrict__ dst_idx, int* __restrict__ wc, int E) {
    __shared__ int cnt[4][NBINS];
    int lane = threadIdx.x & 63, wv = threadIdx.x >> 6;
    int g = blockIdx.x * 4 + wv;
    if (lane < NBINS) cnt[wv][lane] = 0;
    __syncthreads();

    long long E4 = E >> 2;
    long long e0 = 4 * (E4 * g / NW);
    long long e1 = (g == NW - 1) ? (long long)E : 4 * (E4 * (g + 1) / NW);
    for (long long i0 = e0; i0 < e1; i0 += 256) {
        long long i = i0 + 4 * lane;
        if (i < e1) {
            int4 d4 = *reinterpret_cast<const int4*>(dst_idx + i);
            atomicAdd(&cnt[wv][d4.x / BINSZ], 1);
            atomicAdd(&cnt[wv][d4.y / BINSZ], 1);
            atomicAdd(&cnt[wv][d4.z / BINSZ], 1);
            atomicAdd(&cnt[wv][d4.w / BINSZ], 1);
        }
    }
    __syncthreads();
    if (lane < NBINS) wc[lane * NW + g] = cnt[wv][lane];
}

// ---------- 2b) scan pipeline: A) 1024-chunk sums, B) scan chunk sums, C) local scans ----------
__global__ __launch_bounds__(256)
void scanA_kernel(const int* __restrict__ wc, int* __restrict__ bsum) {
    __shared__ int wt[4];
    int t = threadIdx.x, lane = t & 63, wv = t >> 6;
    int4 c = *reinterpret_cast<const int4*>(wc + blockIdx.x * 1024 + 4 * t);
    int s = c.x + c.y + c.z + c.w;
    #pragma unroll
    for (int off = 32; off > 0; off >>= 1) s += __shfl_xor(s, off);
    if (lane == 0) wt[wv] = s;
    __syncthreads();
    if (t == 0) bsum[blockIdx.x] = wt[0] + wt[1] + wt[2] + wt[3];
}

__global__ __launch_bounds__(128)
void scanB_kernel(const int* __restrict__ bsum, int* __restrict__ bbase,
                  int* __restrict__ rbase, int* __restrict__ hist, int nchunk) {
    __shared__ int sb[129];
    __shared__ int wt[2];
    int t = threadIdx.x, lane = t & 63, wv = t >> 6;
    int v = (t < nchunk) ? bsum[t] : 0;
    int inc = v;
    #pragma unroll
    for (int d2 = 1; d2 < 64; d2 <<= 1) { int u = __shfl_up(inc, d2); if (lane >= d2) inc += u; }
    if (lane == 63) wt[wv] = inc;
    __syncthreads();
    int excl = ((wv == 1) ? wt[0] : 0) + inc - v;
    sb[t] = excl;
    if (t == 127) sb[128] = excl + v;   // grand total
    __syncthreads();
    if (t < nchunk) bbase[t] = sb[t];
    if (t < NBINS) {
        int rb = sb[t * (NW / 1024)];
        rbase[t] = rb;
        int nb = (t == NBINS - 1) ? sb[128] : sb[(t + 1) * (NW / 1024)];
        hist[t] = nb - rb;
    }
}

__global__ __launch_bounds__(256)
void scanC_kernel(const int* __restrict__ wc, const int* __restrict__ bbase,
                  int* __restrict__ wbase) {
    __shared__ int wt[4];
    int t = threadIdx.x, lane = t & 63, wv = t >> 6;
    int base = blockIdx.x * 1024 + 4 * t;
    int4 c = *reinterpret_cast<const int4*>(wc + base);
    int s0 = c.x, s1 = s0 + c.y, s2 = s1 + c.z, s3 = s2 + c.w;
    int tot = s3;
    int inc = tot;
    #pragma unroll
    for (int d2 = 1; d2 < 64; d2 <<= 1) { int u = __shfl_up(inc, d2); if (lane >= d2) inc += u; }
    if (lane == 63) wt[wv] = inc;
    __syncthreads();
    int wb = 0;
    for (int k = 0; k < wv; ++k) wb += wt[k];
    int excl = bbase[blockIdx.x] + wb + inc - tot;
    int4 o; o.x = excl; o.y = excl + s0; o.z = excl + s1; o.w = excl + s2;
    *reinterpret_cast<int4*>(wbase + base) = o;
}

// ---------- 2c) place: gather h[s], write {hs,r} records via per-wave LDS cursors ----------
__global__ __launch_bounds__(256)
void place_kernel(const int* __restrict__ src_idx, const int* __restrict__ dst_idx,
                  const float* __restrict__ h, const int* __restrict__ wbase,
                  float* __restrict__ hs_out, unsigned short* __restrict__ rr, int E) {
    __shared__ int ccur[4][NBINS];
    int lane = threadIdx.x & 63, wv = threadIdx.x >> 6;
    int g = blockIdx.x * 4 + wv;
    if (lane < NBINS) ccur[wv][lane] = wbase[lane * NW + g];
    __syncthreads();

    long long E4 = E >> 2;
    long long e0 = 4 * (E4 * g / NW);
    long long e1 = (g == NW - 1) ? (long long)E : 4 * (E4 * (g + 1) / NW);
    for (long long i0 = e0; i0 < e1; i0 += 256) {
        long long i = i0 + 4 * lane;
        if (i < e1) {
            int4 d4 = *reinterpret_cast<const int4*>(dst_idx + i);
            int4 s4 = *reinterpret_cast<const int4*>(src_idx + i);
            float h0 = h[s4.x], h1 = h[s4.y], h2 = h[s4.z], h3 = h[s4.w];
            int b0 = d4.x / BINSZ, b1 = d4.y / BINSZ, b2 = d4.z / BINSZ, b3 = d4.w / BINSZ;
            int p0 = atomicAdd(&ccur[wv][b0], 1);
            int p1 = atomicAdd(&ccur[wv][b1], 1);
            int p2 = atomicAdd(&ccur[wv][b2], 1);
            int p3 = atomicAdd(&ccur[wv][b3], 1);
            hs_out[p0] = h0; rr[p0] = (unsigned short)(d4.x - b0 * BINSZ);
            hs_out[p1] = h1; rr[p1] = (unsigned short)(d4.y - b1 * BINSZ);
            hs_out[p2] = h2; rr[p2] = (unsigned short)(d4.z - b2 * BINSZ);
            hs_out[p3] = h3; rr[p3] = (unsigned short)(d4.w - b3 * BINSZ);
        }
    }
}

// ---------- 2d) gather: pure streaming aggregation (no random global reads) ----------
__global__ __launch_bounds__(1024)
void gather_kernel(const float* __restrict__ hs_s, const unsigned short* __restrict__ rr,
                   const float* __restrict__ ad_h, const float* __restrict__ att_src,
                   const int* __restrict__ rbase, const int* __restrict__ hist,
                   float* __restrict__ part, int SG) {
    __shared__ float s_num[BINSZ];
    __shared__ float s_den[BINSZ];

    int bin   = blockIdx.x / SG;
    int slice = blockIdx.x - bin * SG;
    int r0    = rbase[bin];
    int cnt   = hist[bin];
    long long g0 = r0 + (long long)cnt * slice / SG;
    long long g1 = r0 + (long long)cnt * (slice + 1) / SG;

    for (int k = threadIdx.x; k < BINSZ; k += 1024) { s_num[k] = 0.f; s_den[k] = 0.f; }
    __syncthreads();

    const float as = att_src[0];
    const float* adw = ad_h + bin * BINSZ;   // 32 KB window, stays L1-resident (streams are nt)

    long long i = g0 + threadIdx.x;
    for (; i + 3072 < g1; i += 4096) {
        float h0 = __builtin_nontemporal_load(hs_s + i);
        float h1 = __builtin_nontemporal_load(hs_s + i + 1024);
        float h2 = __builtin_nontemporal_load(hs_s + i + 2048);
        float h3 = __builtin_nontemporal_load(hs_s + i + 3072);
        int r0i = __builtin_nontemporal_load(rr + i);
        int r1i = __builtin_nontemporal_load(rr + i + 1024);
        int r2i = __builtin_nontemporal_load(rr + i + 2048);
        int r3i = __builtin_nontemporal_load(rr + i + 3072);
        float v0 = fmaf(h0, as, adw[r0i]);
        float v1 = fmaf(h1, as, adw[r1i]);
        float v2 = fmaf(h2, as, adw[r2i]);
        float v3 = fmaf(h3, as, adw[r3i]);
        float e0 = __expf(v0 > 0.f ? v0 : NEG_SLOPE * v0);
        float e1 = __expf(v1 > 0.f ? v1 : NEG_SLOPE * v1);
        float e2 = __expf(v2 > 0.f ? v2 : NEG_SLOPE * v2);
        float e3 = __expf(v3 > 0.f ? v3 : NEG_SLOPE * v3);
        atomicAdd(&s_num[r0i], e0 * h0);  atomicAdd(&s_den[r0i], e0);
        atomicAdd(&s_num[r1i], e1 * h1);  atomicAdd(&s_den[r1i], e1);
        atomicAdd(&s_num[r2i], e2 * h2);  atomicAdd(&s_den[r2i], e2);
        atomicAdd(&s_num[r3i], e3 * h3);  atomicAdd(&s_den[r3i], e3);
    }
    for (; i < g1; i += 1024) {
        float h0 = __builtin_nontemporal_load(hs_s + i);
        int   r0i = __builtin_nontemporal_load(rr + i);
        float v0 = fmaf(h0, as, adw[r0i]);
        float e0 = __expf(v0 > 0.f ? v0 : NEG_SLOPE * v0);
        atomicAdd(&s_num[r0i], e0 * h0);
        atomicAdd(&s_den[r0i], e0);
    }
    __syncthreads();

    float* outp = part + (size_t)blockIdx.x * (2 * BINSZ);
    for (int k = threadIdx.x; k < BINSZ; k += 1024) {
        outp[k]         = s_num[k];
        outp[BINSZ + k] = s_den[k];
    }
}

// ---------- 3) reduce copies + self-loop + divide ----------
__global__ void reduce_final(const float* __restrict__ part, const float* __restrict__ h,
                             const float* __restrict__ att_src, const float* __restrict__ att_dst,
                             const float* __restrict__ bias, float* __restrict__ out,
                             int n, int SG) {
    int i = blockIdx.x * blockDim.x + threadIdx.x;
    if (i >= n) return;
    int bin = i / BINSZ;
    int off = i - bin * BINSZ;
    float num = 0.f, den = 0.f;
    const float* p = part + (size_t)(bin * SG) * (2 * BINSZ);
    for (int s = 0; s < SG; ++s) {
        num += p[off];
        den += p[BINSZ + off];
        p += 2 * BINSZ;
    }
    float hv = h[i];
    float v  = hv * (att_src[0] + att_dst[0]);
    float l  = v > 0.0f ? v : NEG_SLOPE * v;
    float e  = __expf(l);
    out[i] = (num + e * hv) / (den + e + 1e-16f) + bias[0];
}

// ---------- fallback: round-3 binned multipass ----------
__global__ __launch_bounds__(1024)
void binpass_kernel(const int* __restrict__ src_idx, const int* __restrict__ dst_idx,
                    const float* __restrict__ h,
                    const float* __restrict__ att_src, const float* __restrict__ att_dst,
                    float* __restrict__ part, int E, int n, int BPB) {
    __shared__ float s_num[BINSZ];
    __shared__ float s_den[BINSZ];

    int bin   = blockIdx.x / BPB;
    int slice = blockIdx.x - bin * BPB;
    int base  = bin * BINSZ;
    int blen  = min(BINSZ, n - base);

    for (int k = threadIdx.x; k < BINSZ; k += 1024) { s_num[k] = 0.f; s_den[k] = 0.f; }
    __syncthreads();

    const float as = att_src[0];
    const float ad = att_dst[0];

    long long e0 = (long long)E * slice / BPB;
    long long e1 = (long long)E * (slice + 1) / BPB;
    for (long long i = e0 + threadIdx.x; i < e1; i += 1024) {
        int d = dst_idx[i];
        unsigned r = (unsigned)(d - base);
        if (r < (unsigned)blen) {
            int s = src_idx[i];
            float hs = h[s];
            float hd = h[d];
            float v  = fmaf(hs, as, hd * ad);
            float l  = v > 0.0f ? v : NEG_SLOPE * v;
            float e  = __expf(l);
            atomicAdd(&s_num[r], e * hs);
            atomicAdd(&s_den[r], e);
        }
    }
    __syncthreads();

    float* outp = part + (size_t)blockIdx.x * (2 * BINSZ);
    for (int k = threadIdx.x; k < BINSZ; k += 1024) {
        outp[k]         = s_num[k];
        outp[BINSZ + k] = s_den[k];
    }
}

__global__ void edge_kernel(const int* __restrict__ src_idx, const int* __restrict__ dst_idx,
                            const float* __restrict__ h,
                            const float* __restrict__ att_src, const float* __restrict__ att_dst,
                            float* __restrict__ nd, int E) {
    const float as = att_src[0];
    const float ad = att_dst[0];
    int i      = blockIdx.x * blockDim.x + threadIdx.x;
    int stride = gridDim.x * blockDim.x;
    for (; i < E; i += stride) {
        int s = src_idx[i];
        int d = dst_idx[i];
        float hs = h[s];
        float hd = h[d];
        float v  = fmaf(hs, as, hd * ad);
        float l  = v > 0.0f ? v : NEG_SLOPE * v;
        float e  = __expf(l);
        unsafeAtomicAdd(&nd[2 * d],     e * hs);
        unsafeAtomicAdd(&nd[2 * d + 1], e);
    }
}

__global__ void final_kernel(const float* __restrict__ h, const float* __restrict__ nd,
                             const float* __restrict__ att_src, const float* __restrict__ att_dst,
                             const float* __restrict__ bias, float* __restrict__ out, int n) {
    int i = blockIdx.x * blockDim.x + threadIdx.x;
    if (i >= n) return;
    float hv = h[i];
    float v  = hv * (att_src[0] + att_dst[0]);
    float l  = v > 0.0f ? v : NEG_SLOPE * v;
    float e  = __expf(l);
    out[i] = (nd[2 * i] + e * hv) / (nd[2 * i + 1] + e + 1e-16f) + bias[0];
}

extern "C" void kernel_launch(void* const* d_in, const int* in_sizes, int n_in,
                              void* d_out, int out_size, void* d_ws, size_t ws_size,
                              hipStream_t stream) {
    const float* x       = (const float*)d_in[0];
    const int*   ei      = (const int*)d_in[1];   // int64 in reference -> int32 here
    const float* W       = (const float*)d_in[2];
    const float* att_src = (const float*)d_in[3];
    const float* att_dst = (const float*)d_in[4];
    const float* bias    = (const float*)d_in[5];
    float*       out     = (float*)d_out;

    const int n = out_size;           // 100000
    const int E = in_sizes[1] / 2;    // 6400000

    const int NELEM  = NBINS * NW;    // 106496
    const int NCHUNK = NELEM / 1024;  // 104

    // ---- workspace layout ----
    size_t off = 0;
    auto alloc = [&](size_t bytes) { size_t p = off; off = (off + bytes + 255) & ~(size_t)255; return p; };
    size_t o_h    = alloc((size_t)n * sizeof(float));
    size_t o_adh  = alloc((size_t)n * sizeof(float));
    size_t o_wc   = alloc((size_t)NELEM * sizeof(int));
    size_t o_wb   = alloc((size_t)NELEM * sizeof(int));
    size_t o_bs   = alloc((size_t)NCHUNK * sizeof(int));
    size_t o_bb   = alloc((size_t)NCHUNK * sizeof(int));
    size_t o_meta = alloc(64 * sizeof(int));            // rbase[13] | hist[13]
    size_t o_hs   = alloc((size_t)E * sizeof(float));
    size_t o_rr   = alloc((size_t)E * sizeof(unsigned short));
    size_t fixed  = off;

    float* h    = (float*)((char*)d_ws + o_h);
    float* ad_h = (float*)((char*)d_ws + o_adh);
    const size_t per = (size_t)2 * BINSZ * sizeof(float);   // 64000 B per partial copy

    proj_kernel<<<2048, 256, 0, stream>>>(x, W, att_dst, h, ad_h, n);

    int SG = 0;
    if (ws_size > fixed) SG = (int)((ws_size - fixed) / ((size_t)NBINS * per));
    if (SG > MAX_SG) SG = MAX_SG;

    bool ok_shape = (n <= NBINS * BINSZ) && ((E & 3) == 0) && (E >= 4 * NW);

    if (SG >= 8 && ok_shape) {
        // ---- primary: deterministic counting sort + streaming gather ----
        int*            wc    = (int*)((char*)d_ws + o_wc);
        int*            wb    = (int*)((char*)d_ws + o_wb);
        int*            bsum  = (int*)((char*)d_ws + o_bs);
        int*            bbase = (int*)((char*)d_ws + o_bb);
        int*            rbase = (int*)((char*)d_ws + o_meta);
        int*            hist  = rbase + 16;
        float*          hs_s  = (float*)((char*)d_ws + o_hs);
        unsigned short* rr    = (unsigned short*)((char*)d_ws + o_rr);
        float*          part  = (float*)((char*)d_ws + fixed);

        count_kernel<<<NW / 4, 256, 0, stream>>>(ei + E, wc, E);
        scanA_kernel<<<NCHUNK, 256, 0, stream>>>(wc, bsum);
        scanB_kernel<<<1, 128, 0, stream>>>(bsum, bbase, rbase, hist, NCHUNK);
        scanC_kernel<<<NCHUNK, 256, 0, stream>>>(wc, bbase, wb);
        place_kernel<<<NW / 4, 256, 0, stream>>>(ei, ei + E, h, wb, hs_s, rr, E);
        gather_kernel<<<NBINS * SG, 1024, 0, stream>>>(hs_s, rr, ad_h, att_src,
                                                       rbase, hist, part, SG);
        reduce_final<<<(n + 255) / 256, 256, 0, stream>>>(part, h, att_src, att_dst,
                                                          bias, out, n, SG);
    } else {
        // ---- fallback: round-3 multipass ----
        size_t hb = (((size_t)n * 2 * sizeof(float)) + 255) & ~(size_t)255;
        int BPB = 0;
        if (ws_size > hb) BPB = (int)((ws_size - hb) / ((size_t)NBINS * per));
        if (BPB > MAX_BPB) BPB = MAX_BPB;

        if (BPB >= 6 && n <= NBINS * BINSZ) {
            float* part = (float*)((char*)d_ws + hb);
            binpass_kernel<<<NBINS * BPB, 1024, 0, stream>>>(
                ei, ei + E, h, att_src, att_dst, part, E, n, BPB);
            reduce_final<<<(n + 255) / 256, 256, 0, stream>>>(
                part, h, att_src, att_dst, bias, out, n, BPB);
        } else {
            float* nd = (float*)((char*)d_ws + hb);
            hipMemsetAsync(nd, 0, (size_t)n * 2 * sizeof(float), stream);
            edge_kernel<<<2048, 256, 0, stream>>>(ei, ei + E, h, att_src, att_dst, nd, E);
            final_kernel<<<(n + 255) / 256, 256, 0, stream>>>(h, nd, att_src, att_dst,
                                                              bias, out, n);
        }
    }
}